// Round 1
// 208.501 us; speedup vs baseline: 1.0642x; 1.0642x over previous
//
#include <hip/hip_runtime.h>
#include <hip/hip_bf16.h>
#include <cstdint>
#include <cstddef>

typedef __attribute__((ext_vector_type(8))) short short8;
typedef __attribute__((ext_vector_type(4))) float f32x4;
typedef __attribute__((ext_vector_type(4))) int int4v;

#define LDK 40  // padded LDS row stride (fallback GEMM only)

// log2(e)/sqrt(DK) = 1.4426950408889634 / 8
#define QSCALE 0.18033688011112042f

__device__ __forceinline__ f32x4 mfma16x16x32(short8 a, short8 b, f32x4 c) {
    return __builtin_amdgcn_mfma_f32_16x16x32_bf16(a, b, c, 0, 0, 0);
}

__device__ __forceinline__ short f2bf(float f) {
    union { __hip_bfloat16 h; short s; } u;
    u.h = __float2bfloat16(f);
    return u.s;
}

__device__ __forceinline__ unsigned short f2bfu(float f) {
    union { __hip_bfloat16 h; unsigned short s; } u;
    u.h = __float2bfloat16(f);
    return u.s;
}

__device__ __forceinline__ float exp2_fast(float x) {
#if __has_builtin(__builtin_amdgcn_exp2f)
    return __builtin_amdgcn_exp2f(x);
#else
    float r;
    asm("v_exp_f32 %0, %1" : "=v"(r) : "v"(x));
    return r;
#endif
}

__device__ __forceinline__ short8 cvt8(f32x4 a, f32x4 b) {
    short8 r;
    r[0] = f2bf(a[0]); r[1] = f2bf(a[1]); r[2] = f2bf(a[2]); r[3] = f2bf(a[3]);
    r[4] = f2bf(b[0]); r[5] = f2bf(b[1]); r[6] = f2bf(b[2]); r[7] = f2bf(b[3]);
    return r;
}

// async global -> LDS, 16B per lane (LDS side wave-uniform base + lane*16)
__device__ __forceinline__ void gload16(const void* g, void* l) {
    __builtin_amdgcn_global_load_lds(
        (__attribute__((address_space(1))) void*)g,
        (__attribute__((address_space(3))) void*)l,
        16, 0, 0);
}

// ---------------- fp32 -> bf16 conversion pass ----------------
struct CvtN { const float* s[7]; short* d[7]; int n[7]; };
__global__ __launch_bounds__(256)
void cvt_n(CvtN a)
{
    const int y = blockIdx.y;
    const int n = a.n[y];
    int i = (blockIdx.x * 256 + threadIdx.x) * 8;
    if (i >= n) return;
    f32x4 x = *(const f32x4*)(a.s[y] + i);
    f32x4 z = *(const f32x4*)(a.s[y] + i + 4);
    *(short8*)(a.d[y] + i) = cvt8(x, z);
}

// ======== BK=64 GEMM core, global_load_lds staging, XOR-8 swizzle ========
// LDS tile rows = 64 shorts (128B = 8 x 16B chunks). element (row,col) at
// row*64 + (((col>>3) ^ (row&7))<<3) + (col&7). Measured 0-conflict pattern.
// Staging: each gload16 instruction covers 8 rows x 8 chunks = 1KB contiguous
// LDS; lane supplies global chunk g = (lane&7) ^ ((lane>>3)&7) of row
// base + (lane>>3). K-loop: 16 iters of 64.

struct QKV2 { const short* A[3]; const short* W[3]; short* dst[3]; const int* mask; };

// Fused QKV (all-bf16): grid (32, 8, 3), 128x128 tile, BK=64, LDS 32KB.
// Epilogue: z=0 scaled by log2e/8 (exp2 softmax downstream); z=1/2 rows
// (K) / cols (V^T) at masked positions are ZEROED so flash_attn needs no
// additive bias: masked score = exactly 0, exp2(0) = 1, corrected by
// subtracting the masked count from the softmax denominator.
__global__ __launch_bounds__(256, 3)
void gemm_qkv_lds(QKV2 P)
{
    constexpr int K = 1024;
    __shared__ short lA[128 * 64];
    __shared__ short lB[128 * 64];
    const int z = blockIdx.z;
    const short* __restrict__ A = P.A[z];
    const short* __restrict__ W = P.W[z];
    const int tid  = threadIdx.x;
    const int lane = tid & 63;
    const int wave = tid >> 6;
    const int quad = lane >> 4;
    const int l16  = lane & 15;
    const int wr   = wave >> 1;
    const int wc   = wave & 1;
    const int m0 = blockIdx.x * 128;
    const int n0 = blockIdx.y * 128;

    const int rsub = lane >> 3;                       // 0..7 row within 8-row group
    const int gch  = (lane & 7) ^ ((lane >> 3) & 7);  // swizzled global chunk

    // per-slot global row bases (A and B): wave*32 + t*8
    const short* gA[4]; const short* gB[4]; short* dA[4]; short* dB[4];
    #pragma unroll
    for (int t = 0; t < 4; t++) {
        int rb = wave * 32 + t * 8;
        gA[t] = A + (size_t)(m0 + rb + rsub) * K + gch * 8;
        gB[t] = W + (size_t)(n0 + rb + rsub) * K + gch * 8;
        dA[t] = lA + rb * 64;
        dB[t] = lB + rb * 64;
    }
    const int skA = l16 & 7;  // frag-read swizzle key (row&7)

    f32x4 acc[4][4] = {};

    for (int k0 = 0; k0 < K; k0 += 64) {
        __syncthreads();                   // prior reads done before overwrite
        #pragma unroll
        for (int t = 0; t < 4; t++) { gload16(gA[t], dA[t]); gA[t] += 64; }
        #pragma unroll
        for (int t = 0; t < 4; t++) { gload16(gB[t], dB[t]); gB[t] += 64; }
        __syncthreads();                   // drains vmcnt -> tile ready
        short8 af[4][2], bfr[4][2];
        #pragma unroll
        for (int i = 0; i < 4; i++)
            #pragma unroll
            for (int c = 0; c < 2; c++)
                af[i][c] = *(const short8*)(lA + (wr * 64 + i * 16 + l16) * 64 +
                                            (((c * 4 + quad) ^ skA) << 3));
        #pragma unroll
        for (int j = 0; j < 4; j++)
            #pragma unroll
            for (int c = 0; c < 2; c++)
                bfr[j][c] = *(const short8*)(lB + (wc * 64 + j * 16 + l16) * 64 +
                                             (((c * 4 + quad) ^ skA) << 3));
        #pragma unroll
        for (int c = 0; c < 2; c++)
            #pragma unroll
            for (int i = 0; i < 4; i++)
                #pragma unroll
                for (int j = 0; j < 4; j++)
                    acc[i][j] = mfma16x16x32(af[i][c], bfr[j][c], acc[i][j]);
    }

    short* dst = P.dst[z];
    const int* __restrict__ mk = P.mask;
    // per-(i,r) multiplier: Q-scale for z=0, mask-zeroing for K/V
    float fac[4][4];
    #pragma unroll
    for (int i = 0; i < 4; i++)
      #pragma unroll
      for (int r = 0; r < 4; r++) {
        int gm = m0 + wr * 64 + i * 16 + quad * 4 + r;
        int bb = gm >> 11, s = gm & 2047;
        fac[i][r] = (z == 0) ? QSCALE
                             : (mk[bb * 2048 + s] ? 1.0f : 0.0f);
      }
    #pragma unroll
    for (int i = 0; i < 4; i++)
      #pragma unroll
      for (int j = 0; j < 4; j++)
        #pragma unroll
        for (int r = 0; r < 4; r++) {
            int gm = m0 + wr * 64 + i * 16 + quad * 4 + r;
            int gn = n0 + wc * 64 + j * 16 + l16;
            float val = acc[i][j][r] * fac[i][r];
            int bb = gm >> 11, s = gm & 2047, h = gn >> 6, d = gn & 63;
            if (z < 2) {
                dst[((size_t)(bb * 16 + h) * 2048 + s) * 64 + d] = f2bf(val);
            } else {
                int sp = (s & ~31) | (2 * (s & 15)) | ((s >> 4) & 1);
                dst[((size_t)(bb * 16 + h) * 64 + d) * 2048 + sp] = f2bf(val);
            }
        }
}

// Output projection: 64x128 tiles, grid (64, 8) = 512 blocks (2/CU), BK=64.
// Wave w handles all 64 m-rows x 32 n-cols at n-offset w*32. LDS 24KB.
__global__ __launch_bounds__(256, 3)
void gemm_out_lds(const short* __restrict__ A, const short* __restrict__ W,
                  float* __restrict__ dst)
{
    constexpr int K = 1024;
    __shared__ short lA[64 * 64];
    __shared__ short lB[128 * 64];
    const int tid  = threadIdx.x;
    const int lane = tid & 63;
    const int wave = tid >> 6;
    const int quad = lane >> 4;
    const int l16  = lane & 15;
    const int m0 = blockIdx.x * 64;
    const int n0 = blockIdx.y * 128;

    const int rsub = lane >> 3;
    const int gch  = (lane & 7) ^ ((lane >> 3) & 7);

    const short* gA[2]; const short* gB[4]; short* dA[2]; short* dB[4];
    #pragma unroll
    for (int t = 0; t < 2; t++) {
        int rb = wave * 16 + t * 8;
        gA[t] = A + (size_t)(m0 + rb + rsub) * K + gch * 8;
        dA[t] = lA + rb * 64;
    }
    #pragma unroll
    for (int t = 0; t < 4; t++) {
        int rb = wave * 32 + t * 8;
        gB[t] = W + (size_t)(n0 + rb + rsub) * K + gch * 8;
        dB[t] = lB + rb * 64;
    }
    const int skA = l16 & 7;

    f32x4 acc[4][2] = {};

    for (int k0 = 0; k0 < K; k0 += 64) {
        __syncthreads();
        #pragma unroll
        for (int t = 0; t < 2; t++) { gload16(gA[t], dA[t]); gA[t] += 64; }
        #pragma unroll
        for (int t = 0; t < 4; t++) { gload16(gB[t], dB[t]); gB[t] += 64; }
        __syncthreads();
        short8 af[4][2], bfr[2][2];
        #pragma unroll
        for (int i = 0; i < 4; i++)
            #pragma unroll
            for (int c = 0; c < 2; c++)
                af[i][c] = *(const short8*)(lA + (i * 16 + l16) * 64 +
                                            (((c * 4 + quad) ^ skA) << 3));
        #pragma unroll
        for (int j = 0; j < 2; j++)
            #pragma unroll
            for (int c = 0; c < 2; c++)
                bfr[j][c] = *(const short8*)(lB + (wave * 32 + j * 16 + l16) * 64 +
                                             (((c * 4 + quad) ^ skA) << 3));
        #pragma unroll
        for (int c = 0; c < 2; c++)
            #pragma unroll
            for (int i = 0; i < 4; i++)
                #pragma unroll
                for (int j = 0; j < 2; j++)
                    acc[i][j] = mfma16x16x32(af[i][c], bfr[j][c], acc[i][j]);
    }

    #pragma unroll
    for (int i = 0; i < 4; i++)
      #pragma unroll
      for (int j = 0; j < 2; j++)
        #pragma unroll
        for (int r = 0; r < 4; r++) {
            int gm = m0 + i * 16 + quad * 4 + r;
            int gn = n0 + wave * 32 + j * 16 + l16;
            dst[(size_t)gm * 1024 + gn] = acc[i][j][r];
        }
}

// ---------------- fallback QKV (fp32 A staged with in-loop cvt) ----------------
struct QKVPtrs { const float* A[3]; const short* W[3]; short* dst[3]; const int* mask; };
__global__ __launch_bounds__(256)
void gemm_qkv_mixed(QKVPtrs P)
{
    constexpr int K = 1024;
    __shared__ short lA[128 * LDK];
    __shared__ short lB[128 * LDK];
    const int z = blockIdx.z;
    const float* __restrict__ A = P.A[z];
    const short* __restrict__ W = P.W[z];
    short* __restrict__ dst = P.dst[z];
    const int tid  = threadIdx.x;
    const int lane = tid & 63;
    const int wave = tid >> 6;
    const int quad = lane >> 4;
    const int l16  = lane & 15;
    const int wr   = wave >> 1;
    const int wc   = wave & 1;
    const int m0 = blockIdx.x * 128;
    const int n0 = blockIdx.y * 128;
    const int c0 = tid, c1 = tid + 256;
    const int r0 = c0 >> 2, o0 = (c0 & 3) * 8;
    const int r1 = c1 >> 2, o1 = (c1 & 3) * 8;

    f32x4 acc[4][4] = {};

    for (int k0 = 0; k0 < K; k0 += 32) {
        f32x4 a00 = *(const f32x4*)(A + (size_t)(m0 + r0) * K + k0 + o0);
        f32x4 a01 = *(const f32x4*)(A + (size_t)(m0 + r0) * K + k0 + o0 + 4);
        f32x4 a10 = *(const f32x4*)(A + (size_t)(m0 + r1) * K + k0 + o1);
        f32x4 a11 = *(const f32x4*)(A + (size_t)(m0 + r1) * K + k0 + o1 + 4);
        short8 b0 = *(const short8*)(W + (size_t)(n0 + r0) * K + k0 + o0);
        short8 b1 = *(const short8*)(W + (size_t)(n0 + r1) * K + k0 + o1);
        short8 a0 = cvt8(a00, a01);
        short8 a1 = cvt8(a10, a11);
        __syncthreads();
        *(short8*)(lA + r0 * LDK + o0) = a0;
        *(short8*)(lA + r1 * LDK + o1) = a1;
        *(short8*)(lB + r0 * LDK + o0) = b0;
        *(short8*)(lB + r1 * LDK + o1) = b1;
        __syncthreads();
        short8 af[4], bfr[4];
        #pragma unroll
        for (int i = 0; i < 4; i++)
            af[i] = *(const short8*)(lA + (wr * 64 + i * 16 + l16) * LDK + quad * 8);
        #pragma unroll
        for (int j = 0; j < 4; j++)
            bfr[j] = *(const short8*)(lB + (wc * 64 + j * 16 + l16) * LDK + quad * 8);
        #pragma unroll
        for (int i = 0; i < 4; i++)
            #pragma unroll
            for (int j = 0; j < 4; j++)
                acc[i][j] = mfma16x16x32(af[i], bfr[j], acc[i][j]);
    }

    const int* __restrict__ mk = P.mask;
    float fac[4][4];
    #pragma unroll
    for (int i = 0; i < 4; i++)
      #pragma unroll
      for (int r = 0; r < 4; r++) {
        int gm = m0 + wr * 64 + i * 16 + quad * 4 + r;
        int bb = gm >> 11, s = gm & 2047;
        fac[i][r] = (z == 0) ? QSCALE
                             : (mk[bb * 2048 + s] ? 1.0f : 0.0f);
      }
    #pragma unroll
    for (int i = 0; i < 4; i++)
      #pragma unroll
      for (int j = 0; j < 4; j++)
        #pragma unroll
        for (int r = 0; r < 4; r++) {
            int gm = m0 + wr * 64 + i * 16 + quad * 4 + r;
            int gn = n0 + wc * 64 + j * 16 + l16;
            float val = acc[i][j][r] * fac[i][r];
            int bb = gm >> 11, s = gm & 2047, h = gn >> 6, d = gn & 63;
            if (z < 2) {
                dst[((size_t)(bb * 16 + h) * 2048 + s) * 64 + d] = f2bf(val);
            } else {
                int sp = (s & ~31) | (2 * (s & 15)) | ((s >> 4) & 1);
                dst[((size_t)(bb * 16 + h) * 64 + d) * 2048 + sp] = f2bf(val);
            }
        }
}

// ---------------- flash attention (bias-free, exp2, setprio) ----------------
// Masked K rows / V cols are pre-zeroed by the QKV GEMM, so masked scores are
// exactly 0 -> exp2(0) = 1.0 exactly; each block subtracts the per-batch
// masked count Mb from the softmax denominator. Q carries log2e/8 so the
// softmax is a raw v_exp_f32.
__global__ __launch_bounds__(256, 3)
void flash_attn(const short* __restrict__ Qp, const short* __restrict__ Kp,
                const short* __restrict__ Vt, const int* __restrict__ mask,
                short* __restrict__ AO)
{
    __shared__ short lK[2][64 * 64];
    __shared__ short lV[2][64 * 64];
    __shared__ short lP[8][16 * 64];
    __shared__ int sMcnt;
    const int tid  = threadIdx.x;
    const int lane = tid & 63;
    const int wave = tid >> 6;
    const int quad = lane >> 4;
    const int l16  = lane & 15;
    const int bh = blockIdx.y;
    const int b  = bh >> 4;
    const int h  = bh & 15;
    const int q0 = blockIdx.x * 128 + wave * 32;

    if (tid == 0) sMcnt = 0;
    {
        const int* mb = mask + b * 2048;
        int cnt = 0;
        for (int j = tid; j < 2048; j += 256) cnt += (mb[j] == 0) ? 1 : 0;
        #pragma unroll
        for (int off = 1; off < 64; off <<= 1) cnt += __shfl_xor(cnt, off);
        __syncthreads();               // sMcnt init visible
        if (lane == 0) atomicAdd(&sMcnt, cnt);
    }

    const short* Qb = Qp + (size_t)bh * 2048 * 64;
    const short* Kb = Kp + (size_t)bh * 2048 * 64;
    const short* Vb = Vt + (size_t)bh * 64 * 2048;

    short8 qf[2][2];
    #pragma unroll
    for (int t = 0; t < 2; t++)
        #pragma unroll
        for (int c = 0; c < 2; c++)
            qf[t][c] = *(const short8*)(Qb + (q0 + t * 16 + l16) * 64 + c * 32 + quad * 8);

    const int c0 = tid, c1 = tid + 256;
    const int r0 = c0 >> 3, cc0 = c0 & 7;
    const int r1 = c1 >> 3, cc1 = c1 & 7;
    const int lo0 = r0 * 64 + ((cc0 ^ (r0 & 7)) << 3);
    const int lo1 = r1 * 64 + ((cc1 ^ (r1 & 7)) << 3);

    int4v kr0, kr1, vr0, vr1;
    auto prefetch = [&](int kt) {
        kr0 = *(const int4v*)(Kb + (size_t)(kt + r0) * 64 + cc0 * 8);
        kr1 = *(const int4v*)(Kb + (size_t)(kt + r1) * 64 + cc1 * 8);
        vr0 = *(const int4v*)(Vb + (size_t)r0 * 2048 + kt + cc0 * 8);
        vr1 = *(const int4v*)(Vb + (size_t)r1 * 2048 + kt + cc1 * 8);
    };
    auto stage = [&](int buf) {
        *(int4v*)(lK[buf] + lo0) = kr0;
        *(int4v*)(lK[buf] + lo1) = kr1;
        *(int4v*)(lV[buf] + lo0) = vr0;
        *(int4v*)(lV[buf] + lo1) = vr1;
    };

    prefetch(0);
    stage(0);
    __syncthreads();                   // tile 0 staged AND sMcnt complete
    const float Mb = (float)sMcnt;

    float lsum[2][4] = {};
    f32x4 o[2][4] = {};
    short* lp[2] = { lP[wave * 2], lP[wave * 2 + 1] };

    for (int ti = 0; ti < 32; ti++) {
        const int cur = ti & 1;
        const int kt = ti * 64;
        if (ti < 31) prefetch(kt + 64);
        const short* K_ = lK[cur];
        const short* V_ = lV[cur];

        f32x4 s[2][4];
        __builtin_amdgcn_s_setprio(1);
        #pragma unroll
        for (int kk = 0; kk < 4; kk++) {
            int row = kk * 16 + l16;
            short8 kf0 = *(const short8*)(K_ + row * 64 + ((quad ^ (row & 7)) << 3));
            short8 kf1 = *(const short8*)(K_ + row * 64 + (((4 + quad) ^ (row & 7)) << 3));
            #pragma unroll
            for (int t = 0; t < 2; t++) {
                f32x4 z = {};
                z = mfma16x16x32(qf[t][0], kf0, z);
                z = mfma16x16x32(qf[t][1], kf1, z);
                s[t][kk] = z;
            }
        }
        __builtin_amdgcn_s_setprio(0);

        #pragma unroll
        for (int t = 0; t < 2; t++)
            #pragma unroll
            for (int g = 0; g < 2; g++)
                #pragma unroll
                for (int r = 0; r < 4; r++) {
                    float p0 = exp2_fast(s[t][2 * g][r]);
                    float p1 = exp2_fast(s[t][2 * g + 1][r]);
                    lsum[t][r] += p0 + p1;
                    unsigned pk = (unsigned)f2bfu(p0) | ((unsigned)f2bfu(p1) << 16);
                    int row = quad * 4 + r;
                    int ch  = 4 * g + (l16 >> 2);
                    *(unsigned*)(lp[t] + row * 64 + ((ch ^ (row & 7)) << 3) + ((2 * l16) & 7)) = pk;
                }
        __builtin_amdgcn_s_waitcnt(0xC07F);  // lgkmcnt(0): wave's LDS writes done

        short8 pf[2][2];
        #pragma unroll
        for (int t = 0; t < 2; t++)
            #pragma unroll
            for (int c = 0; c < 2; c++)
                pf[t][c] = *(const short8*)(lp[t] + l16 * 64 + (((c * 4 + quad) ^ (l16 & 7)) << 3));
        __builtin_amdgcn_s_setprio(1);
        #pragma unroll
        for (int c = 0; c < 2; c++)
            #pragma unroll
            for (int dt = 0; dt < 4; dt++) {
                int row = dt * 16 + l16;
                short8 vf = *(const short8*)(V_ + row * 64 + (((c * 4 + quad) ^ (row & 7)) << 3));
                o[0][dt] = mfma16x16x32(pf[0][c], vf, o[0][dt]);
                o[1][dt] = mfma16x16x32(pf[1][c], vf, o[1][dt]);
            }
        __builtin_amdgcn_s_setprio(0);

        if (ti < 31) {
            stage(1 - cur);
            __syncthreads();
        }
    }

    #pragma unroll
    for (int off = 1; off < 16; off <<= 1)
        #pragma unroll
        for (int t = 0; t < 2; t++)
            #pragma unroll
            for (int r = 0; r < 4; r++)
                lsum[t][r] += __shfl_xor(lsum[t][r], off);

    #pragma unroll
    for (int t = 0; t < 2; t++)
        #pragma unroll
        for (int r = 0; r < 4; r++) {
            float inv = 1.0f / (lsum[t][r] - Mb);
            int sidx = q0 + t * 16 + quad * 4 + r;
            size_t base = ((size_t)(b * 2048 + sidx)) * 1024 + (size_t)h * 64;
            #pragma unroll
            for (int dt = 0; dt < 4; dt++)
                AO[base + dt * 16 + l16] = f2bf(o[t][dt][r] * inv);
        }
}

extern "C" void kernel_launch(void* const* d_in, const int* in_sizes, int n_in,
                              void* d_out, int out_size, void* d_ws, size_t ws_size,
                              hipStream_t stream)
{
    const float* q  = (const float*)d_in[0];
    const float* k  = (const float*)d_in[1];
    const float* v  = (const float*)d_in[2];
    const int* mask = (const int*)d_in[3];
    const float* wq = (const float*)d_in[4];
    const float* wk = (const float*)d_in[5];
    const float* wv = (const float*)d_in[6];
    const float* wo = (const float*)d_in[7];

    short* ws = (short*)d_ws;
    const bool big = ws_size >= (size_t)67108864;  // 33.55M shorts

    if (big) {
        short* qb  = ws;
        short* kb  = ws + 4194304;
        short* vb  = ws + 8388608;
        short* wqb = ws + 12582912;
        short* wkb = ws + 13631488;
        short* wvb = ws + 14680064;
        short* wob = ws + 15728640;
        short* Qp  = ws + 16777216;
        short* Kp  = ws + 20971520;
        short* Vt  = ws + 25165824;
        short* AO  = ws + 29360128;

        CvtN C;
        C.s[0] = q;  C.s[1] = k;  C.s[2] = v;
        C.s[3] = wq; C.s[4] = wk; C.s[5] = wv; C.s[6] = wo;
        C.d[0] = qb;  C.d[1] = kb;  C.d[2] = vb;
        C.d[3] = wqb; C.d[4] = wkb; C.d[5] = wvb; C.d[6] = wob;
        C.n[0] = C.n[1] = C.n[2] = 4194304;
        C.n[3] = C.n[4] = C.n[5] = C.n[6] = 1048576;
        hipLaunchKernelGGL(cvt_n, dim3(2048, 7), dim3(256), 0, stream, C);

        QKV2 P;
        P.A[0] = qb;  P.A[1] = kb;  P.A[2] = vb;
        P.W[0] = wqb; P.W[1] = wkb; P.W[2] = wvb;
        P.dst[0] = Qp; P.dst[1] = Kp; P.dst[2] = Vt;
        P.mask = mask;
        hipLaunchKernelGGL(gemm_qkv_lds, dim3(32, 8, 3), dim3(256), 0, stream, P);

        hipLaunchKernelGGL(flash_attn, dim3(16, 32), dim3(256), 0, stream,
                           Qp, Kp, Vt, mask, AO);
        hipLaunchKernelGGL(gemm_out_lds, dim3(64, 8), dim3(256), 0, stream,
                           AO, wob, (float*)d_out);
    } else {
        short* wqb = ws;
        short* wkb = ws + 1048576;
        short* wvb = ws + 2097152;
        short* wob = ws + 3145728;
        short* Qp  = ws + 4194304;
        short* Kp  = ws + 8388608;
        short* Vt  = ws + 12582912;
        short* AO  = ws + 16777216;

        CvtN C;
        C.s[0] = wq; C.s[1] = wk; C.s[2] = wv; C.s[3] = wo;
        C.d[0] = wqb; C.d[1] = wkb; C.d[2] = wvb; C.d[3] = wob;
        C.n[0] = C.n[1] = C.n[2] = C.n[3] = 1048576;
        C.s[4] = C.s[5] = C.s[6] = wq; C.d[4] = C.d[5] = C.d[6] = wqb;
        C.n[4] = C.n[5] = C.n[6] = 0;
        hipLaunchKernelGGL(cvt_n, dim3(512, 4), dim3(256), 0, stream, C);

        QKVPtrs P;
        P.A[0] = q;  P.A[1] = k;  P.A[2] = v;
        P.W[0] = wqb; P.W[1] = wkb; P.W[2] = wvb;
        P.dst[0] = Qp; P.dst[1] = Kp; P.dst[2] = Vt;
        P.mask = mask;
        hipLaunchKernelGGL(gemm_qkv_mixed, dim3(32, 8, 3), dim3(256), 0, stream, P);

        hipLaunchKernelGGL(flash_attn, dim3(16, 32), dim3(256), 0, stream,
                           Qp, Kp, Vt, mask, AO);
        hipLaunchKernelGGL(gemm_out_lds, dim3(64, 8), dim3(256), 0, stream,
                           AO, wob, (float*)d_out);
    }
}